// Round 1
// baseline (213.671 us; speedup 1.0000x reference)
//
#include <hip/hip_runtime.h>

// BrewCnnLayer: x(2048,784) -> reshape (b,1,28,28)
//   conv1: W1 (10,49) as (10,1,7,7), VALID -> (b,10,22,22); relu + ratio1
//   conv2: W2 (10,250) as (10,10,5,5), VALID -> (b,10,18,18); relu + ratio2
// out = [ h2 (b*10*324) | rat1 (b*10*484) | rat2 (b*10*324) ]  (f32)
//
// Fused: one block per image; image + conv1 activations staged in LDS.
// fp32 vector compute (no fp32 MFMA on CDNA4; bf16 would flip ratio signs).

#define THREADS 256

__global__ __launch_bounds__(THREADS) void brewcnn_fused(
    const float* __restrict__ x,    // (nimg, 784)
    const float* __restrict__ Wa,   // (10, 49)
    const float* __restrict__ Wb,   // (10, 250)
    float* __restrict__ out,
    int nimg)
{
    __shared__ float s_x[28 * 28];          // 3136 B
    __shared__ float s_h[10][22 * 22];      // 19360 B

    const int img = blockIdx.x;
    const int tid = threadIdx.x;

    // ---- load image to LDS (float4-vectorized, coalesced) ----
    {
        const float4* xin = reinterpret_cast<const float4*>(x + img * 784);
        float4* sx4 = reinterpret_cast<float4*>(s_x);
        for (int i = tid; i < 196; i += THREADS) sx4[i] = xin[i];
    }
    __syncthreads();

    const int h2_base = img * 3240;                       // 10*18*18
    const int r1_base = nimg * 3240 + img * 4840;         // 10*22*22
    const int r2_base = nimg * 3240 + nimg * 4840 + img * 3240;

    // ---- conv1 (7x7, 1->10 ch) + relu + ratio1; h1 stays in LDS ----
    for (int p = tid; p < 484; p += THREADS) {
        const int py = p / 22;
        const int px = p - py * 22;
        float acc[10];
        #pragma unroll
        for (int oc = 0; oc < 10; ++oc) acc[oc] = 0.0f;

        #pragma unroll
        for (int ky = 0; ky < 7; ++ky) {
            #pragma unroll
            for (int kx = 0; kx < 7; ++kx) {
                const float v = s_x[(py + ky) * 28 + (px + kx)];
                #pragma unroll
                for (int oc = 0; oc < 10; ++oc)
                    acc[oc] = fmaf(v, Wa[oc * 49 + ky * 7 + kx], acc[oc]);
            }
        }

        #pragma unroll
        for (int oc = 0; oc < 10; ++oc) {
            const float h = acc[oc];
            s_h[oc][p] = h > 0.0f ? h : 0.0f;
            // ratio: h>0 -> h/h == 1.0 exactly; h<0 -> 0/h == -0.0; h==0 -> NaN->0
            out[r1_base + oc * 484 + p] = h > 0.0f ? 1.0f : 0.0f;
        }
    }
    __syncthreads();

    // ---- conv2 (5x5, 10->10 ch) + relu + ratio2 ----
    for (int p = tid; p < 324; p += THREADS) {
        const int py = p / 18;
        const int px = p - py * 18;
        float acc[10];
        #pragma unroll
        for (int oc = 0; oc < 10; ++oc) acc[oc] = 0.0f;

        for (int ic = 0; ic < 10; ++ic) {
            const float* __restrict__ srow = &s_h[ic][0];
            const float* __restrict__ wrow = Wb + ic * 25;   // + oc*250 inside
            #pragma unroll
            for (int ky = 0; ky < 5; ++ky) {
                #pragma unroll
                for (int kx = 0; kx < 5; ++kx) {
                    const float v = srow[(py + ky) * 22 + (px + kx)];
                    #pragma unroll
                    for (int oc = 0; oc < 10; ++oc)
                        acc[oc] = fmaf(v, wrow[oc * 250 + ky * 5 + kx], acc[oc]);
                }
            }
        }

        #pragma unroll
        for (int oc = 0; oc < 10; ++oc) {
            const float h = acc[oc];
            out[h2_base + oc * 324 + p] = h > 0.0f ? h : 0.0f;
            out[r2_base + oc * 324 + p] = h > 0.0f ? 1.0f : 0.0f;
        }
    }
}

extern "C" void kernel_launch(void* const* d_in, const int* in_sizes, int n_in,
                              void* d_out, int out_size, void* d_ws, size_t ws_size,
                              hipStream_t stream) {
    const float* x  = (const float*)d_in[0];
    const float* Wa = (const float*)d_in[1];
    const float* Wb = (const float*)d_in[2];
    float* out = (float*)d_out;
    const int nimg = in_sizes[0] / 784;

    brewcnn_fused<<<nimg, THREADS, 0, stream>>>(x, Wa, Wb, out, nimg);
}

// Round 2
// 161.653 us; speedup vs baseline: 1.3218x; 1.3218x over previous
//
#include <hip/hip_runtime.h>

// BrewCnnLayer fused: one block per image (2048 blocks x 256 threads).
//   conv1: W1 (10,1,7,7) VALID -> (10,22,22); relu + ratio1
//   conv2: W2 (10,10,5,5) VALID -> (10,18,18); relu + ratio2
// out = [ h2 (b*3240) | rat1 (b*4840) | rat2 (b*3240) ]  (f32)
//
// Row-strip decomposition: thread = (oc, output row). All weights + image +
// h1 live in LDS; inputs read as aligned ds_read_b128 (rows padded to
// 16B multiples: s_x stride 28 floats = 112B, s_h stride 24 floats = 96B).
// Weights for the current tap row are held in registers -> >90% of VALU
// issue is v_fmac_f32. fp32 vector math (no fp32 MFMA on CDNA4; bf16 would
// flip ratio signs near zero).

#define THREADS 256

__global__ __launch_bounds__(THREADS, 4) void brewcnn_fused(
    const float* __restrict__ x,    // (nimg, 784)
    const float* __restrict__ Wa,   // (10, 49)
    const float* __restrict__ Wb,   // (10, 250)
    float* __restrict__ out,
    int nimg)
{
    __shared__ __align__(16) float s_x[28 * 28];        // 3136 B
    __shared__ __align__(16) float s_h[10][22 * 24];    // 21120 B (rows padded 22->24)
    __shared__ __align__(16) float s_wa[490];           // 1960 B
    __shared__ __align__(16) float s_wb[2500];          // 10000 B  => 36.2 KB total

    const int img = blockIdx.x;
    const int tid = threadIdx.x;

    // ---- stage image + weights into LDS (vectorized, coalesced) ----
    if (tid < 196)
        reinterpret_cast<float4*>(s_x)[tid] =
            reinterpret_cast<const float4*>(x + img * 784)[tid];
    if (tid < 122)
        reinterpret_cast<float4*>(s_wa)[tid] =
            reinterpret_cast<const float4*>(Wa)[tid];
    if (tid < 2) s_wa[488 + tid] = Wa[488 + tid];
    for (int i = tid; i < 625; i += THREADS)
        reinterpret_cast<float4*>(s_wb)[i] =
            reinterpret_cast<const float4*>(Wb)[i];
    __syncthreads();

    const int h2_base = img * 3240;
    const int r1_base = nimg * 3240 + img * 4840;
    const int r2_base = nimg * 8080 + img * 3240;

    // ---- conv1: task = (oc, row), 220 tasks ----
    if (tid < 220) {
        const int row = tid / 10;          // 0..21  (lanes of a wave share rows)
        const int oc  = tid - row * 10;    // 0..9
        float acc[22];
#pragma unroll
        for (int i = 0; i < 22; ++i) acc[i] = 0.0f;

        const float* wrow = s_wa + oc * 49;
        for (int ky = 0; ky < 7; ++ky) {
            float in[28];
            const float4* rp = reinterpret_cast<const float4*>(s_x + (row + ky) * 28);
#pragma unroll
            for (int j = 0; j < 7; ++j) {
                float4 v = rp[j];
                in[4*j] = v.x; in[4*j+1] = v.y; in[4*j+2] = v.z; in[4*j+3] = v.w;
            }
            float w[7];
#pragma unroll
            for (int k = 0; k < 7; ++k) w[k] = wrow[ky * 7 + k];
#pragma unroll
            for (int kx = 0; kx < 7; ++kx)
#pragma unroll
                for (int px = 0; px < 22; ++px)
                    acc[px] = fmaf(in[px + kx], w[kx], acc[px]);
        }

        // epilogue: relu into LDS, ratio1 to global
        float r1v[22];
#pragma unroll
        for (int px = 0; px < 22; ++px) {
            const float h = acc[px];
            acc[px] = h > 0.0f ? h : 0.0f;
            r1v[px] = h > 0.0f ? 1.0f : 0.0f;
        }
        float* hdst = &s_h[oc][row * 24];
#pragma unroll
        for (int j = 0; j < 5; ++j)
            reinterpret_cast<float4*>(hdst)[j] =
                make_float4(acc[4*j], acc[4*j+1], acc[4*j+2], acc[4*j+3]);
        hdst[20] = acc[20];
        hdst[21] = acc[21];

        float* r1p = out + r1_base + oc * 484 + row * 22;
#pragma unroll
        for (int j = 0; j < 11; ++j)
            reinterpret_cast<float2*>(r1p)[j] = make_float2(r1v[2*j], r1v[2*j+1]);
    }
    __syncthreads();

    // ---- conv2: task = (oc, row), 180 tasks ----
    if (tid < 180) {
        const int row = tid / 10;          // 0..17
        const int oc  = tid - row * 10;    // 0..9
        float acc[18];
#pragma unroll
        for (int i = 0; i < 18; ++i) acc[i] = 0.0f;

        const float* wbase = s_wb + oc * 250;
#pragma unroll 1
        for (int ic = 0; ic < 10; ++ic) {
            const float* hbase = &s_h[ic][0];
            const float* wic = wbase + ic * 25;
            for (int ky = 0; ky < 5; ++ky) {
                float in[24];
                const float4* rp = reinterpret_cast<const float4*>(hbase + (row + ky) * 24);
#pragma unroll
                for (int j = 0; j < 6; ++j) {
                    float4 v = rp[j];
                    in[4*j] = v.x; in[4*j+1] = v.y; in[4*j+2] = v.z; in[4*j+3] = v.w;
                }
                float w[5];
#pragma unroll
                for (int k = 0; k < 5; ++k) w[k] = wic[ky * 5 + k];
#pragma unroll
                for (int kx = 0; kx < 5; ++kx)
#pragma unroll
                    for (int px = 0; px < 18; ++px)
                        acc[px] = fmaf(in[px + kx], w[kx], acc[px]);
            }
        }

        // epilogue: h2 + ratio2 to global
        float hv[18], rv[18];
#pragma unroll
        for (int px = 0; px < 18; ++px) {
            const float h = acc[px];
            hv[px] = h > 0.0f ? h : 0.0f;
            rv[px] = h > 0.0f ? 1.0f : 0.0f;
        }
        float* h2p = out + h2_base + oc * 324 + row * 18;
        float* r2p = out + r2_base + oc * 324 + row * 18;
#pragma unroll
        for (int j = 0; j < 9; ++j) {
            reinterpret_cast<float2*>(h2p)[j] = make_float2(hv[2*j], hv[2*j+1]);
            reinterpret_cast<float2*>(r2p)[j] = make_float2(rv[2*j], rv[2*j+1]);
        }
    }
}

extern "C" void kernel_launch(void* const* d_in, const int* in_sizes, int n_in,
                              void* d_out, int out_size, void* d_ws, size_t ws_size,
                              hipStream_t stream) {
    const float* x  = (const float*)d_in[0];
    const float* Wa = (const float*)d_in[1];
    const float* Wb = (const float*)d_in[2];
    float* out = (float*)d_out;
    const int nimg = in_sizes[0] / 784;

    brewcnn_fused<<<nimg, THREADS, 0, stream>>>(x, Wa, Wb, out, nimg);
}